// Round 6
// baseline (870.164 us; speedup 1.0000x reference)
//
#include <hip/hip_runtime.h>

#define USER_NUM 100000
#define ITEM_NUM 50000
#define NN (USER_NUM + ITEM_NUM)
#define EMB 64
#define N_EDGES 8000000
#define EPS_C 0.1f
#define PROTO 4000

// ---------------- old-path params (kept verbatim as ws fallback) ----------------
#define BSHIFT 6
#define BROWS 64                                // rows per bucket
#define NB ((NN + BROWS - 1) / BROWS)           // 2344 buckets
#define NSUB 8
#define CAPS 608
#define WIN (NSUB * CAPS)
#define CAP 4608

// ---------------- hierarchical split params ----------------
#define SBSHIFT 9
#define SBROWS 512                              // rows per super-bin
#define NSB ((NN + SBROWS - 1) / SBROWS)        // 293 super-bins
#define SCAP 28160                              // slots/super-bin; mean 27304, +5.2 sigma
#define SF_STRIDE 16                            // pad sfill counters to one 64B line each
// chunk-sort scatter
#define CHS 8192                                // edges per block chunk (LDS-resident)
#define NCH ((N_EDGES + CHS - 1) / CHS)         // 977 blocks

static __device__ __forceinline__ unsigned short f32_to_bf16_rne(float f) {
    unsigned u = __float_as_uint(f);
    u += 0x7FFFu + ((u >> 16) & 1u);
    return (unsigned short)(u >> 16);
}
static __device__ __forceinline__ float bf16_to_f32(unsigned short h) {
    return __uint_as_float(((unsigned)h) << 16);
}
static __device__ __forceinline__ float bf16_lo(unsigned u) {
    return __uint_as_float(u << 16);
}
static __device__ __forceinline__ float bf16_hi(unsigned u) {
    return __uint_as_float(u & 0xFFFF0000u);
}
static __device__ __forceinline__ unsigned pack_bf16(float lo, float hi) {
    return (unsigned)f32_to_bf16_rne(lo) | ((unsigned)f32_to_bf16_rne(hi) << 16);
}

// ---------- non-temporal (streaming) loads: don't allocate in cache hierarchy ----------
typedef unsigned u32x2_t __attribute__((ext_vector_type(2)));
typedef unsigned u32x4_t __attribute__((ext_vector_type(4)));
typedef int      i32x4_t __attribute__((ext_vector_type(4)));
typedef float    f32x4_t __attribute__((ext_vector_type(4)));

static __device__ __forceinline__ uint2 ntload_u2(const uint2* p) {
    u32x2_t v = __builtin_nontemporal_load((const u32x2_t*)p);
    uint2 r; r.x = v.x; r.y = v.y; return r;
}
static __device__ __forceinline__ uint4 ntload_u4(const uint4* p) {
    u32x4_t v = __builtin_nontemporal_load((const u32x4_t*)p);
    uint4 r; r.x = v.x; r.y = v.y; r.z = v.z; r.w = v.w; return r;
}
static __device__ __forceinline__ int4 ntload_i4(const int4* p) {
    i32x4_t v = __builtin_nontemporal_load((const i32x4_t*)p);
    int4 r; r.x = v.x; r.y = v.y; r.z = v.z; r.w = v.w; return r;
}
static __device__ __forceinline__ float4 ntload_f4(const float4* p) {
    f32x4_t v = __builtin_nontemporal_load((const f32x4_t*)p);
    float4 r; r.x = v.x; r.y = v.y; r.z = v.z; r.w = v.w; return r;
}

// ---------- concat + quantize to bf16 (float4 -> ushort4) ----------
__global__ __launch_bounds__(256) void concat_bf16_kernel(const float* __restrict__ u,
                                                          const float* __restrict__ it,
                                                          unsigned short* __restrict__ out) {
    long i4 = (long)blockIdx.x * 256 + threadIdx.x;
    const long usz4 = (long)USER_NUM * EMB / 4;
    const long tot4 = (long)NN * EMB / 4;
    if (i4 >= tot4) return;
    const float4* src = (i4 < usz4) ? (const float4*)u : (const float4*)it;
    long j = (i4 < usz4) ? i4 : (i4 - usz4);
    float4 v = ntload_f4(&src[j]);              // read-once stream
    ushort4 o;
    o.x = f32_to_bf16_rne(v.x); o.y = f32_to_bf16_rne(v.y);
    o.z = f32_to_bf16_rne(v.z); o.w = f32_to_bf16_rne(v.w);
    ((ushort4*)out)[i4] = o;                    // cached: next spmm gathers this
}

// ================= chunk counting-sort scatter (single shot per block) =================
__global__ __launch_bounds__(256) void chunk_sort_scatter(const int* __restrict__ rows,
                                                          const int* __restrict__ cols,
                                                          const float* __restrict__ vals,
                                                          int* __restrict__ sfill,
                                                          uint2* __restrict__ sbuf) {
    __shared__ unsigned skey[CHS];              // 32 KB
    __shared__ unsigned sval[CHS];              // 32 KB
    __shared__ int hist[NSB];
    __shared__ int pref[NSB + 1];
    __shared__ int gbase[NSB];
    __shared__ int fill[NSB];

    const int tid   = threadIdx.x;
    const int start = blockIdx.x * CHS;
    const int n     = (start + CHS <= N_EDGES) ? CHS : (N_EDGES - start);
    const int n4    = n >> 2;                   // all chunk sizes are multiples of 4

    for (int b = tid; b < NSB; b += 256) { hist[b] = 0; fill[b] = 0; }
    __syncthreads();

    // phase 1: histogram (vectorized nt row read)
    const int4* rows4 = (const int4*)(rows + start);
    for (int i = tid; i < n4; i += 256) {
        int4 r = ntload_i4(&rows4[i]);
        atomicAdd(&hist[r.x >> SBSHIFT], 1);
        atomicAdd(&hist[r.y >> SBSHIFT], 1);
        atomicAdd(&hist[r.z >> SBSHIFT], 1);
        atomicAdd(&hist[r.w >> SBSHIFT], 1);
    }
    __syncthreads();

    // exclusive prefix scan over 293 bins: wave-0 shuffle scan
    if (tid < 64) {
        int carry = 0;
        #pragma unroll
        for (int g = 0; g < (NSB + 63) / 64; ++g) {
            int idx = g * 64 + tid;
            int h = (idx < NSB) ? hist[idx] : 0;
            int v = h;
            #pragma unroll
            for (int off = 1; off < 64; off <<= 1) {
                int t = __shfl_up(v, off, 64);
                if (tid >= off) v += t;
            }
            if (idx < NSB) pref[idx] = carry + v - h;
            carry += __shfl(v, 63, 64);
        }
        if (tid == 0) pref[NSB] = carry;
    }
    __syncthreads();

    // reserve global space: one padded-line atomic per non-empty (block,bin)
    for (int b = tid; b < NSB; b += 256)
        gbase[b] = hist[b] ? atomicAdd(&sfill[b * SF_STRIDE], hist[b]) : 0;

    // phase 2: scatter edges into LDS at sorted positions (nt edge reads)
    const int4*   cols4 = (const int4*)(cols + start);
    const float4* vals4 = (const float4*)(vals + start);
    for (int i = tid; i < n4; i += 256) {
        int4   r = ntload_i4(&rows4[i]);
        int4   c = ntload_i4(&cols4[i]);
        float4 v = ntload_f4(&vals4[i]);
        {
            int b = r.x >> SBSHIFT; int p = pref[b] + atomicAdd(&fill[b], 1);
            skey[p] = ((unsigned)r.x & (SBROWS - 1)) | ((unsigned)c.x << SBSHIFT);
            sval[p] = __float_as_uint(v.x);
        }
        {
            int b = r.y >> SBSHIFT; int p = pref[b] + atomicAdd(&fill[b], 1);
            skey[p] = ((unsigned)r.y & (SBROWS - 1)) | ((unsigned)c.y << SBSHIFT);
            sval[p] = __float_as_uint(v.y);
        }
        {
            int b = r.z >> SBSHIFT; int p = pref[b] + atomicAdd(&fill[b], 1);
            skey[p] = ((unsigned)r.z & (SBROWS - 1)) | ((unsigned)c.z << SBSHIFT);
            sval[p] = __float_as_uint(v.z);
        }
        {
            int b = r.w >> SBSHIFT; int p = pref[b] + atomicAdd(&fill[b], 1);
            skey[p] = ((unsigned)r.w & (SBROWS - 1)) | ((unsigned)c.w << SBSHIFT);
            sval[p] = __float_as_uint(v.w);
        }
    }
    __syncthreads();

    // phase 3: stream sorted chunk out; consecutive threads -> consecutive slots
    for (int j = tid; j < n; j += 256) {
        int lo = 0, hi = NSB;                   // largest b with pref[b] <= j
        while (hi - lo > 1) {
            int mid = (lo + hi) >> 1;
            if (pref[mid] <= j) lo = mid; else hi = mid;
        }
        int gpos = gbase[lo] + (j - pref[lo]);
        if (gpos < SCAP) {
            uint2 pk; pk.x = skey[j]; pk.y = sval[j];
            sbuf[(size_t)lo * SCAP + gpos] = pk;
        }
    }
}

// ================= per-super-bin row sort (fused) =================
__global__ __launch_bounds__(512) void bin_rowsort(const int* __restrict__ sfill,
                                                   const uint2* __restrict__ sbuf,
                                                   uint2* __restrict__ dst,
                                                   int* __restrict__ row_start,
                                                   int* __restrict__ row_cnt) {
    __shared__ int hist[SBROWS], pref[SBROWS], fill[SBROWS];   // 6 KB
    const int s = blockIdx.x, tid = threadIdx.x;
    int total = sfill[s * SF_STRIDE]; if (total > SCAP) total = SCAP;
    const uint2* src = sbuf + (size_t)s * SCAP;

    for (int r = tid; r < SBROWS; r += 512) { hist[r] = 0; fill[r] = 0; }
    __syncthreads();

    const int n2 = total >> 1;
    const uint4* src4 = (const uint4*)src;      // window base is 16B-aligned
    for (int i = tid; i < n2; i += 512) {
        uint4 q = src4[i];
        atomicAdd(&hist[q.x & (SBROWS - 1)], 1);
        atomicAdd(&hist[q.z & (SBROWS - 1)], 1);
    }
    if (tid == 0 && (total & 1)) atomicAdd(&hist[src[total - 1].x & (SBROWS - 1)], 1);
    __syncthreads();

    if (tid < 64) {
        int carry = 0;
        #pragma unroll
        for (int g = 0; g < SBROWS / 64; ++g) {
            int idx = g * 64 + tid;
            int h = hist[idx];
            int v = h;
            #pragma unroll
            for (int off = 1; off < 64; off <<= 1) {
                int t = __shfl_up(v, off, 64);
                if (tid >= off) v += t;
            }
            pref[idx] = carry + v - h;
            carry += __shfl(v, 63, 64);
        }
    }
    __syncthreads();

    uint2* dwin = dst + (size_t)s * SCAP;
    for (int i = tid; i < n2; i += 512) {
        uint4 q = src4[i];
        {
            int r = (int)(q.x & (SBROWS - 1));
            int p = pref[r] + atomicAdd(&fill[r], 1);
            uint2 o; o.x = q.x >> SBSHIFT; o.y = q.y;   // {col, valbits}
            dwin[p] = o;
        }
        {
            int r = (int)(q.z & (SBROWS - 1));
            int p = pref[r] + atomicAdd(&fill[r], 1);
            uint2 o; o.x = q.z >> SBSHIFT; o.y = q.w;
            dwin[p] = o;
        }
    }
    if (tid == 0 && (total & 1)) {
        uint2 pk = src[total - 1];
        int r = (int)(pk.x & (SBROWS - 1));
        int p = pref[r] + atomicAdd(&fill[r], 1);
        uint2 o; o.x = pk.x >> SBSHIFT; o.y = pk.y;
        dwin[p] = o;
    }
    if (tid < SBROWS) {
        int row = s * SBROWS + tid;
        if (row < NN) { row_start[row] = s * SCAP + pref[tid]; row_cnt[row] = hist[tid]; }
    }
}

// ---------- fused CSR SpMM: 8 edges/wave-instr (8 lanes x 8 bf16 per edge-row) ----------
// nt on csr + noise (read-once streams) keeps the L3 free for the x gather table.
__global__ __launch_bounds__(256) void spmm_csr_fused(const int* __restrict__ row_start,
                                                      const int* __restrict__ row_cnt,
                                                      const uint2* __restrict__ csr,
                                                      const unsigned short* __restrict__ x,
                                                      const float* __restrict__ noise_k,
                                                      unsigned short* __restrict__ ego_out,
                                                      float* __restrict__ acc,
                                                      int mode) {
    int row  = (blockIdx.x * 256 + threadIdx.x) >> 6;
    int lane = threadIdx.x & 63;
    if (row >= NN) return;
    const int slot = lane >> 3;                  // 0..7: which edge in the group of 8
    const int m    = lane & 7;                   // dims 8m..8m+7
    const unsigned moff = (unsigned)m << 3;      // element offset within the x row

    int s   = row_start[row];
    int end = s + row_cnt[row];

    float a0 = 0.f, a1 = 0.f, a2 = 0.f, a3 = 0.f;
    float a4 = 0.f, a5 = 0.f, a6 = 0.f, a7 = 0.f;
    float b0 = 0.f, b1 = 0.f, b2 = 0.f, b3 = 0.f;
    float b4 = 0.f, b5 = 0.f, b6 = 0.f, b7 = 0.f;
    int e = s;
    for (; e + 16 <= end; e += 16) {
        uint2 pA = ntload_u2(&csr[e + slot]);
        uint2 pB = ntload_u2(&csr[e + 8 + slot]);
        uint4 gA = *(const uint4*)(x + (((unsigned)pA.x) << 6) + moff);   // cached gather
        uint4 gB = *(const uint4*)(x + (((unsigned)pB.x) << 6) + moff);
        float vA = __uint_as_float(pA.y);
        float vB = __uint_as_float(pB.y);
        a0 += vA * bf16_lo(gA.x); a1 += vA * bf16_hi(gA.x);
        a2 += vA * bf16_lo(gA.y); a3 += vA * bf16_hi(gA.y);
        a4 += vA * bf16_lo(gA.z); a5 += vA * bf16_hi(gA.z);
        a6 += vA * bf16_lo(gA.w); a7 += vA * bf16_hi(gA.w);
        b0 += vB * bf16_lo(gB.x); b1 += vB * bf16_hi(gB.x);
        b2 += vB * bf16_lo(gB.y); b3 += vB * bf16_hi(gB.y);
        b4 += vB * bf16_lo(gB.z); b5 += vB * bf16_hi(gB.z);
        b6 += vB * bf16_lo(gB.w); b7 += vB * bf16_hi(gB.w);
    }
    for (; e < end; e += 8) {                    // masked tail groups of 8
        int idx = e + slot;
        uint2 p = make_uint2(0u, 0u);
        if (idx < end) p = ntload_u2(&csr[idx]);
        uint4 g = *(const uint4*)(x + (((unsigned)p.x) << 6) + moff);
        float v = __uint_as_float(p.y);          // 0 for masked lanes
        a0 += v * bf16_lo(g.x); a1 += v * bf16_hi(g.x);
        a2 += v * bf16_lo(g.y); a3 += v * bf16_hi(g.y);
        a4 += v * bf16_lo(g.z); a5 += v * bf16_hi(g.z);
        a6 += v * bf16_lo(g.w); a7 += v * bf16_hi(g.w);
    }
    a0 += b0; a1 += b1; a2 += b2; a3 += b3;
    a4 += b4; a5 += b5; a6 += b6; a7 += b7;

    // combine the 8 slots: dims 8m..8m+7 summed across slot groups
    #pragma unroll
    for (int off = 8; off < 64; off <<= 1) {
        a0 += __shfl_xor(a0, off, 64);
        a1 += __shfl_xor(a1, off, 64);
        a2 += __shfl_xor(a2, off, 64);
        a3 += __shfl_xor(a3, off, 64);
        a4 += __shfl_xor(a4, off, 64);
        a5 += __shfl_xor(a5, off, 64);
        a6 += __shfl_xor(a6, off, 64);
        a7 += __shfl_xor(a7, off, 64);
    }

    if (slot == 0) {                             // 8 lanes handle the full row, 8 dims each
        size_t base4 = (size_t)row * 16 + ((unsigned)m << 1);   // float4 index
        float4 n0 = ntload_f4(&((const float4*)noise_k)[base4]);
        float4 n1 = ntload_f4(&((const float4*)noise_k)[base4 + 1]);
        float ss = n0.x * n0.x + n0.y * n0.y + n0.z * n0.z + n0.w * n0.w
                 + n1.x * n1.x + n1.y * n1.y + n1.z * n1.z + n1.w * n1.w;
        #pragma unroll
        for (int off = 1; off < 8; off <<= 1) ss += __shfl_xor(ss, off, 64);
        float inv = EPS_C / fmaxf(sqrtf(ss), 1e-12f);

        float e0 = fmaf(((a0 > 0.f) ? 1.f : ((a0 < 0.f) ? -1.f : 0.f)) * n0.x, inv, a0);
        float e1 = fmaf(((a1 > 0.f) ? 1.f : ((a1 < 0.f) ? -1.f : 0.f)) * n0.y, inv, a1);
        float e2 = fmaf(((a2 > 0.f) ? 1.f : ((a2 < 0.f) ? -1.f : 0.f)) * n0.z, inv, a2);
        float e3 = fmaf(((a3 > 0.f) ? 1.f : ((a3 < 0.f) ? -1.f : 0.f)) * n0.w, inv, a3);
        float e4 = fmaf(((a4 > 0.f) ? 1.f : ((a4 < 0.f) ? -1.f : 0.f)) * n1.x, inv, a4);
        float e5 = fmaf(((a5 > 0.f) ? 1.f : ((a5 < 0.f) ? -1.f : 0.f)) * n1.y, inv, a5);
        float e6 = fmaf(((a6 > 0.f) ? 1.f : ((a6 < 0.f) ? -1.f : 0.f)) * n1.z, inv, a6);
        float e7 = fmaf(((a7 > 0.f) ? 1.f : ((a7 < 0.f) ? -1.f : 0.f)) * n1.w, inv, a7);

        uint4 o;
        o.x = pack_bf16(e0, e1); o.y = pack_bf16(e2, e3);
        o.z = pack_bf16(e4, e5); o.w = pack_bf16(e6, e7);
        ((uint4*)ego_out)[(size_t)row * 8 + m] = o;   // cached: next dispatch's x

        float4* accp = (float4*)acc + base4;          // cached: next dispatch re-reads
        if (mode == 0) {
            accp[0] = make_float4(e0, e1, e2, e3);
            accp[1] = make_float4(e4, e5, e6, e7);
        } else if (mode == 1) {
            float4 c0 = accp[0], c1 = accp[1];
            c0.x += e0; c0.y += e1; c0.z += e2; c0.w += e3;
            c1.x += e4; c1.y += e5; c1.z += e6; c1.w += e7;
            accp[0] = c0; accp[1] = c1;
        } else {
            float4 c0 = accp[0], c1 = accp[1];
            c0.x = (c0.x + e0) * (1.0f / 3.0f); c0.y = (c0.y + e1) * (1.0f / 3.0f);
            c0.z = (c0.z + e2) * (1.0f / 3.0f); c0.w = (c0.w + e3) * (1.0f / 3.0f);
            c1.x = (c1.x + e4) * (1.0f / 3.0f); c1.y = (c1.y + e5) * (1.0f / 3.0f);
            c1.z = (c1.z + e6) * (1.0f / 3.0f); c1.w = (c1.w + e7) * (1.0f / 3.0f);
            accp[0] = c0; accp[1] = c1;
        }
    }
}

// ================= OLD PATH (verbatim fallback) =================
__global__ __launch_bounds__(256) void bucket_scatter_fixed(const int* __restrict__ rows,
                                                            const int* __restrict__ cols,
                                                            const float* __restrict__ vals,
                                                            int* __restrict__ bfill,
                                                            uint2* __restrict__ bbuf) {
    int e = blockIdx.x * 256 + threadIdx.x;
    if (e >= N_EDGES) return;
    int sub = blockIdx.x & (NSUB - 1);
    int r = rows[e];
    int b = r >> BSHIFT;
    int pos = atomicAdd(&bfill[b * NSUB + sub], 1);
    if (pos < CAPS) {
        uint2 pk;
        pk.x = (unsigned)(r & (BROWS - 1)) | ((unsigned)cols[e] << BSHIFT);
        pk.y = __float_as_uint(vals[e]);
        bbuf[(size_t)b * WIN + sub * CAPS + pos] = pk;
    }
}

__global__ __launch_bounds__(256) void bucket_sort_fixed(const int* __restrict__ bfill,
                                                         uint2* __restrict__ bbuf,
                                                         int* __restrict__ row_start,
                                                         int* __restrict__ row_cnt) {
    __shared__ uint2 buf[CAP];
    __shared__ int scnt[NSUB], soff[NSUB];
    __shared__ int h[BROWS], pref[BROWS], fill[BROWS];
    int b = blockIdx.x;
    int tid = threadIdx.x;
    if (tid < NSUB) {
        int c = bfill[b * NSUB + tid];
        scnt[tid] = (c < CAPS) ? c : CAPS;
    }
    if (tid < BROWS) { h[tid] = 0; fill[tid] = 0; }
    __syncthreads();
    if (tid == 0) {
        int run = 0;
        #pragma unroll
        for (int s = 0; s < NSUB; ++s) { soff[s] = run; run += scnt[s]; }
    }
    __syncthreads();
    int total = soff[NSUB - 1] + scnt[NSUB - 1];
    if (total > CAP) total = CAP;
    for (int s = 0; s < NSUB; ++s) {
        int c = scnt[s], off = soff[s];
        const uint2* src = bbuf + (size_t)b * WIN + s * CAPS;
        for (int i = tid; i < c; i += 256)
            if (off + i < CAP) buf[off + i] = src[i];
    }
    __syncthreads();
    for (int i = tid; i < total; i += 256) atomicAdd(&h[buf[i].x & (BROWS - 1)], 1);
    __syncthreads();
    if (tid == 0) {
        int run = 0;
        #pragma unroll
        for (int r = 0; r < BROWS; ++r) { pref[r] = run; run += h[r]; }
    }
    __syncthreads();
    uint2* dst = bbuf + (size_t)b * WIN;
    for (int i = tid; i < total; i += 256) {
        unsigned m = buf[i].x;
        int rl = (int)(m & (BROWS - 1));
        int pos = pref[rl] + atomicAdd(&fill[rl], 1);
        uint2 pk;
        pk.x = m >> BSHIFT;
        pk.y = buf[i].y;
        dst[pos] = pk;
    }
    if (tid < BROWS) {
        int row = b * BROWS + tid;
        if (row < NN) { row_start[row] = b * WIN + pref[tid]; row_cnt[row] = h[tid]; }
    }
}

// old-path spmm (wave-per-row, scalar bf16 gather) — kept for fallback branch
__global__ __launch_bounds__(256) void spmm_csr_old(const int* __restrict__ row_start,
                                                    const int* __restrict__ row_cnt,
                                                    const uint2* __restrict__ csr,
                                                    const unsigned short* __restrict__ x,
                                                    const float* __restrict__ noise_k,
                                                    unsigned short* __restrict__ ego_out,
                                                    float* __restrict__ acc,
                                                    int mode) {
    int row = (blockIdx.x * 256 + threadIdx.x) >> 6;
    int lane = threadIdx.x & 63;
    if (row >= NN) return;
    int s = row_start[row];
    int end = s + row_cnt[row];
    float a0 = 0.f, a1 = 0.f, a2 = 0.f, a3 = 0.f;
    int e = s;
    for (; e + 4 <= end; e += 4) {
        uint2 p0 = csr[e], p1 = csr[e + 1], p2 = csr[e + 2], p3 = csr[e + 3];
        a0 += __uint_as_float(p0.y) * bf16_to_f32(x[(size_t)p0.x * EMB + lane]);
        a1 += __uint_as_float(p1.y) * bf16_to_f32(x[(size_t)p1.x * EMB + lane]);
        a2 += __uint_as_float(p2.y) * bf16_to_f32(x[(size_t)p2.x * EMB + lane]);
        a3 += __uint_as_float(p3.y) * bf16_to_f32(x[(size_t)p3.x * EMB + lane]);
    }
    for (; e < end; ++e) {
        uint2 p = csr[e];
        a0 += __uint_as_float(p.y) * bf16_to_f32(x[(size_t)p.x * EMB + lane]);
    }
    float a = (a0 + a1) + (a2 + a3);
    size_t idx = (size_t)row * EMB + lane;
    float nv = noise_k[idx];
    float ss = nv * nv;
    #pragma unroll
    for (int off = 32; off >= 1; off >>= 1) ss += __shfl_xor(ss, off, 64);
    float nrm = fmaxf(sqrtf(ss), 1e-12f);
    float sgn = (a > 0.0f) ? 1.0f : ((a < 0.0f) ? -1.0f : 0.0f);
    float e1 = a + sgn * (nv / nrm) * EPS_C;
    ego_out[idx] = f32_to_bf16_rne(e1);
    if (mode == 0)      acc[idx] = e1;
    else if (mode == 1) acc[idx] += e1;
    else                acc[idx] = (acc[idx] + e1) * (1.0f / 3.0f);
}

// ---------- fallback: fp32 atomic path (needs 76.8 MB ws) ----------
__global__ __launch_bounds__(256) void concat_f32_kernel(const float* __restrict__ u,
                                                         const float* __restrict__ it,
                                                         float* __restrict__ out) {
    long i = (long)blockIdx.x * 256 + threadIdx.x;
    const long usz = (long)USER_NUM * EMB;
    const long tot = (long)NN * EMB;
    if (i >= tot) return;
    out[i] = (i < usz) ? u[i] : it[i - usz];
}

__global__ __launch_bounds__(256) void spmm_atomic_kernel(const int* __restrict__ rows,
                                                          const int* __restrict__ cols,
                                                          const float* __restrict__ vals,
                                                          const float* __restrict__ x,
                                                          float* __restrict__ y) {
    long t = (long)blockIdx.x * 256 + threadIdx.x;
    int e = (int)(t >> 6);
    int lane = (int)(t & 63);
    if (e >= N_EDGES) return;
    atomicAdd(&y[(long)rows[e] * EMB + lane], vals[e] * x[(long)cols[e] * EMB + lane]);
}

__global__ __launch_bounds__(256) void noise_acc_kernel(float* __restrict__ ego,
                                                        const float* __restrict__ noise_k,
                                                        float* __restrict__ acc,
                                                        int mode) {
    long t = (long)blockIdx.x * 256 + threadIdx.x;
    int node = (int)(t >> 6);
    int lane = (int)(t & 63);
    if (node >= NN) return;
    long idx = (long)node * EMB + lane;
    float nv = noise_k[idx];
    float s = nv * nv;
    #pragma unroll
    for (int off = 32; off >= 1; off >>= 1) s += __shfl_xor(s, off, 64);
    float nrm = fmaxf(sqrtf(s), 1e-12f);
    float e0 = ego[idx];
    float sgn = (e0 > 0.0f) ? 1.0f : ((e0 < 0.0f) ? -1.0f : 0.0f);
    float e1 = e0 + sgn * (nv / nrm) * EPS_C;
    ego[idx] = e1;
    if (mode == 0)      acc[idx] = e1;
    else if (mode == 1) acc[idx] += e1;
    else                acc[idx] = (acc[idx] + e1) * (1.0f / 3.0f);
}

extern "C" void kernel_launch(void* const* d_in, const int* in_sizes, int n_in,
                              void* d_out, int out_size, void* d_ws, size_t ws_size,
                              hipStream_t stream) {
    const float* user_emb   = (const float*)d_in[0];
    const float* item_emb   = (const float*)d_in[1];
    const float* user_proto = (const float*)d_in[2];
    const float* item_proto = (const float*)d_in[3];
    const int*   rows       = (const int*)d_in[4];
    const int*   cols       = (const int*)d_in[5];
    const float* vals       = (const float*)d_in[6];
    const float* noise      = (const float*)d_in[7];
    float* out = (float*)d_out;

    const size_t EGO_BF = ((size_t)NN * EMB * sizeof(unsigned short) + 255) & ~(size_t)255;
    const size_t NARR   = ((size_t)NN * sizeof(int) + 255) & ~(size_t)255;

    // ---- new path layout (~172 MB) ----
    const size_t SBUF_SZ  = (size_t)NSB * SCAP * sizeof(uint2);      // 66.0 MB
    const size_t DST_SZ   = (size_t)NSB * SCAP * sizeof(uint2);      // 66.0 MB (row-sorted)
    const size_t SFILL_SZ = ((size_t)NSB * SF_STRIDE * sizeof(int) + 255) & ~(size_t)255;
    const size_t required_new = 2 * EGO_BF + SBUF_SZ + DST_SZ + 2 * NARR + SFILL_SZ;

    // ---- old path layout (~131 MB) ----
    const size_t BBUF   = (size_t)NB * WIN * sizeof(uint2);
    const size_t FARR   = ((size_t)NB * NSUB * sizeof(int) + 255) & ~(size_t)255;
    const size_t required_old = 2 * EGO_BF + BBUF + 2 * NARR + FARR;

    float* acc = out;
    const int elemTotal  = NN * EMB;
    const int elemBlocks = (elemTotal + 255) / 256;
    const int vecBlocks  = (elemTotal / 4 + 255) / 256;
    const int edgeBlocks = (N_EDGES + 255) / 256;
    const int rowWaveBlocks = (NN + 3) / 4;

    if (ws_size >= required_new) {
        char* p = (char*)d_ws;
        unsigned short* egoA = (unsigned short*)p;  p += EGO_BF;
        unsigned short* egoB = (unsigned short*)p;  p += EGO_BF;
        uint2* sbuf          = (uint2*)p;           p += SBUF_SZ;
        uint2* dstbuf        = (uint2*)p;           p += DST_SZ;
        int* row_start       = (int*)p;             p += NARR;
        int* row_cnt         = (int*)p;             p += NARR;
        int* sfill           = (int*)p;             p += SFILL_SZ;

        concat_bf16_kernel<<<vecBlocks, 256, 0, stream>>>(user_emb, item_emb, egoA);
        hipMemsetAsync(sfill, 0, (size_t)NSB * SF_STRIDE * sizeof(int), stream);
        chunk_sort_scatter<<<NCH, 256, 0, stream>>>(rows, cols, vals, sfill, sbuf);
        bin_rowsort<<<NSB, 512, 0, stream>>>(sfill, sbuf, dstbuf, row_start, row_cnt);

        unsigned short* cur = egoA;
        unsigned short* nxt = egoB;
        for (int k = 0; k < 3; ++k) {
            int mode = (k == 0) ? 0 : ((k == 2) ? 2 : 1);
            spmm_csr_fused<<<rowWaveBlocks, 256, 0, stream>>>(
                row_start, row_cnt, dstbuf, cur,
                noise + (size_t)k * NN * EMB, nxt, acc, mode);
            unsigned short* t = cur; cur = nxt; nxt = t;
        }
    } else if (ws_size >= required_old) {
        char* p = (char*)d_ws;
        unsigned short* egoA = (unsigned short*)p;  p += EGO_BF;
        unsigned short* egoB = (unsigned short*)p;  p += EGO_BF;
        uint2* bbuf          = (uint2*)p;           p += BBUF;
        int* row_start       = (int*)p;             p += NARR;
        int* row_cnt         = (int*)p;             p += NARR;
        int* bfill           = (int*)p;             p += FARR;

        concat_bf16_kernel<<<vecBlocks, 256, 0, stream>>>(user_emb, item_emb, egoA);
        hipMemsetAsync(bfill, 0, (size_t)NB * NSUB * sizeof(int), stream);
        bucket_scatter_fixed<<<edgeBlocks, 256, 0, stream>>>(rows, cols, vals, bfill, bbuf);
        bucket_sort_fixed<<<NB, 256, 0, stream>>>(bfill, bbuf, row_start, row_cnt);

        unsigned short* cur = egoA;
        unsigned short* nxt = egoB;
        for (int k = 0; k < 3; ++k) {
            int mode = (k == 0) ? 0 : ((k == 2) ? 2 : 1);
            spmm_csr_old<<<rowWaveBlocks, 256, 0, stream>>>(
                row_start, row_cnt, bbuf, cur,
                noise + (size_t)k * NN * EMB, nxt, acc, mode);
            unsigned short* t = cur; cur = nxt; nxt = t;
        }
    } else {
        const size_t EGO_SZ = (size_t)NN * EMB * sizeof(float);
        float* fA = (float*)d_ws;
        float* fB = (float*)((char*)d_ws + EGO_SZ);
        concat_f32_kernel<<<elemBlocks, 256, 0, stream>>>(user_emb, item_emb, fA);
        float* cur = fA; float* nxt = fB;
        for (int k = 0; k < 3; ++k) {
            hipMemsetAsync(nxt, 0, EGO_SZ, stream);
            spmm_atomic_kernel<<<N_EDGES / 4, 256, 0, stream>>>(rows, cols, vals, cur, nxt);
            int mode = (k == 0) ? 0 : ((k == 2) ? 2 : 1);
            noise_acc_kernel<<<elemBlocks, 256, 0, stream>>>(
                nxt, noise + (size_t)k * NN * EMB, acc, mode);
            float* t = cur; cur = nxt; nxt = t;
        }
    }

    hipMemcpyAsync(out + (size_t)NN * EMB, user_proto,
                   (size_t)PROTO * EMB * sizeof(float), hipMemcpyDeviceToDevice, stream);
    hipMemcpyAsync(out + (size_t)NN * EMB + (size_t)PROTO * EMB, item_proto,
                   (size_t)PROTO * EMB * sizeof(float), hipMemcpyDeviceToDevice, stream);
}

// Round 7
// 836.886 us; speedup vs baseline: 1.0398x; 1.0398x over previous
//
#include <hip/hip_runtime.h>

#define USER_NUM 100000
#define ITEM_NUM 50000
#define NN (USER_NUM + ITEM_NUM)
#define EMB 64
#define N_EDGES 8000000
#define EPS_C 0.1f
#define PROTO 4000

// ---------------- old-path params (kept verbatim as ws fallback) ----------------
#define BSHIFT 6
#define BROWS 64                                // rows per bucket
#define NB ((NN + BROWS - 1) / BROWS)           // 2344 buckets
#define NSUB 8
#define CAPS 608
#define WIN (NSUB * CAPS)
#define CAP 4608

// ---------------- hierarchical split params ----------------
#define SBSHIFT 9
#define SBROWS 512                              // rows per super-bin
#define NSB ((NN + SBROWS - 1) / SBROWS)        // 293 super-bins
#define SCAP 28160                              // slots/super-bin; mean 27304, +5.2 sigma
#define SF_STRIDE 16                            // pad sfill counters to one 64B line each
// chunk-sort scatter
#define CHS 4096                                // edges per block chunk (LDS-resident)
#define NCH ((N_EDGES + CHS - 1) / CHS)         // 1954 blocks
#define RITER (CHS / 4 / 256)                   // 4 row-quad iters per thread

static __device__ __forceinline__ unsigned short f32_to_bf16_rne(float f) {
    unsigned u = __float_as_uint(f);
    u += 0x7FFFu + ((u >> 16) & 1u);
    return (unsigned short)(u >> 16);
}
static __device__ __forceinline__ float bf16_to_f32(unsigned short h) {
    return __uint_as_float(((unsigned)h) << 16);
}
static __device__ __forceinline__ float bf16_lo(unsigned u) {
    return __uint_as_float(u << 16);
}
static __device__ __forceinline__ float bf16_hi(unsigned u) {
    return __uint_as_float(u & 0xFFFF0000u);
}
static __device__ __forceinline__ unsigned pack_bf16(float lo, float hi) {
    return (unsigned)f32_to_bf16_rne(lo) | ((unsigned)f32_to_bf16_rne(hi) << 16);
}

// ---------- concat + quantize to bf16 (float4 -> ushort4) ----------
__global__ __launch_bounds__(256) void concat_bf16_kernel(const float* __restrict__ u,
                                                          const float* __restrict__ it,
                                                          unsigned short* __restrict__ out) {
    long i4 = (long)blockIdx.x * 256 + threadIdx.x;
    const long usz4 = (long)USER_NUM * EMB / 4;
    const long tot4 = (long)NN * EMB / 4;
    if (i4 >= tot4) return;
    const float4* src = (i4 < usz4) ? (const float4*)u : (const float4*)it;
    long j = (i4 < usz4) ? i4 : (i4 - usz4);
    float4 v = src[j];
    ushort4 o;
    o.x = f32_to_bf16_rne(v.x); o.y = f32_to_bf16_rne(v.y);
    o.z = f32_to_bf16_rne(v.z); o.w = f32_to_bf16_rne(v.w);
    ((ushort4*)out)[i4] = o;
}

// ================= chunk counting-sort scatter (binid version, no search) =================
// 45 KB LDS -> 3 blocks/CU; rows held in regs across phases; phase 3 is
// 2 independent LDS reads + 1 coalesced global write per edge.
__global__ __launch_bounds__(256) void chunk_sort_scatter(const int* __restrict__ rows,
                                                          const int* __restrict__ cols,
                                                          const float* __restrict__ vals,
                                                          int* __restrict__ sfill,
                                                          uint2* __restrict__ sbuf) {
    __shared__ uint2 buf[CHS];                  // 32 KB {key, valbits}
    __shared__ unsigned short binid[CHS];       // 8 KB
    __shared__ int hist[NSB];
    __shared__ int pref[NSB + 1];
    __shared__ int gbase[NSB];
    __shared__ int fill[NSB];

    const int tid   = threadIdx.x;
    const int start = blockIdx.x * CHS;
    const int n     = (start + CHS <= N_EDGES) ? CHS : (N_EDGES - start);
    const int n4    = n >> 2;                   // all chunk sizes are multiples of 4

    for (int b = tid; b < NSB; b += 256) { hist[b] = 0; fill[b] = 0; }
    __syncthreads();

    // phase 1: histogram; keep row quads in registers for phase 2
    int4 rloc[RITER];
    const int4* rows4 = (const int4*)(rows + start);
    {
        int it = 0;
        for (int i = tid; i < n4; i += 256, ++it) {
            int4 r = rows4[i];
            rloc[it] = r;
            atomicAdd(&hist[r.x >> SBSHIFT], 1);
            atomicAdd(&hist[r.y >> SBSHIFT], 1);
            atomicAdd(&hist[r.z >> SBSHIFT], 1);
            atomicAdd(&hist[r.w >> SBSHIFT], 1);
        }
    }
    __syncthreads();

    // exclusive prefix scan over 293 bins: wave-0 shuffle scan
    if (tid < 64) {
        int carry = 0;
        #pragma unroll
        for (int g = 0; g < (NSB + 63) / 64; ++g) {
            int idx = g * 64 + tid;
            int h = (idx < NSB) ? hist[idx] : 0;
            int v = h;
            #pragma unroll
            for (int off = 1; off < 64; off <<= 1) {
                int t = __shfl_up(v, off, 64);
                if (tid >= off) v += t;
            }
            if (idx < NSB) pref[idx] = carry + v - h;
            carry += __shfl(v, 63, 64);
        }
        if (tid == 0) pref[NSB] = carry;
    }
    __syncthreads();

    // reserve global space: one padded-line atomic per non-empty (block,bin)
    for (int b = tid; b < NSB; b += 256)
        gbase[b] = hist[b] ? atomicAdd(&sfill[b * SF_STRIDE], hist[b]) : 0;

    // phase 2: scatter edges into LDS at sorted positions, record bin per slot
    const int4*   cols4 = (const int4*)(cols + start);
    const float4* vals4 = (const float4*)(vals + start);
    {
        int it = 0;
        for (int i = tid; i < n4; i += 256, ++it) {
            int4   r = rloc[it];
            int4   c = cols4[i];
            float4 v = vals4[i];
            {
                int b = r.x >> SBSHIFT; int p = pref[b] + atomicAdd(&fill[b], 1);
                buf[p] = make_uint2(((unsigned)r.x & (SBROWS - 1)) | ((unsigned)c.x << SBSHIFT),
                                    __float_as_uint(v.x));
                binid[p] = (unsigned short)b;
            }
            {
                int b = r.y >> SBSHIFT; int p = pref[b] + atomicAdd(&fill[b], 1);
                buf[p] = make_uint2(((unsigned)r.y & (SBROWS - 1)) | ((unsigned)c.y << SBSHIFT),
                                    __float_as_uint(v.y));
                binid[p] = (unsigned short)b;
            }
            {
                int b = r.z >> SBSHIFT; int p = pref[b] + atomicAdd(&fill[b], 1);
                buf[p] = make_uint2(((unsigned)r.z & (SBROWS - 1)) | ((unsigned)c.z << SBSHIFT),
                                    __float_as_uint(v.z));
                binid[p] = (unsigned short)b;
            }
            {
                int b = r.w >> SBSHIFT; int p = pref[b] + atomicAdd(&fill[b], 1);
                buf[p] = make_uint2(((unsigned)r.w & (SBROWS - 1)) | ((unsigned)c.w << SBSHIFT),
                                    __float_as_uint(v.w));
                binid[p] = (unsigned short)b;
            }
        }
    }
    __syncthreads();

    // phase 3: stream sorted chunk out; consecutive threads -> consecutive slots
    for (int j = tid; j < n; j += 256) {
        int b = binid[j];
        int g = gbase[b] + (j - pref[b]);
        if (g < SCAP) sbuf[(size_t)b * SCAP + g] = buf[j];
    }
}

// ================= per-super-bin row sort (fused) =================
__global__ __launch_bounds__(512) void bin_rowsort(const int* __restrict__ sfill,
                                                   const uint2* __restrict__ sbuf,
                                                   uint2* __restrict__ dst,
                                                   int* __restrict__ row_start,
                                                   int* __restrict__ row_cnt) {
    __shared__ int hist[SBROWS], pref[SBROWS], fill[SBROWS];   // 6 KB
    const int s = blockIdx.x, tid = threadIdx.x;
    int total = sfill[s * SF_STRIDE]; if (total > SCAP) total = SCAP;
    const uint2* src = sbuf + (size_t)s * SCAP;

    for (int r = tid; r < SBROWS; r += 512) { hist[r] = 0; fill[r] = 0; }
    __syncthreads();

    const int n2 = total >> 1;
    const uint4* src4 = (const uint4*)src;      // window base is 16B-aligned
    for (int i = tid; i < n2; i += 512) {
        uint4 q = src4[i];
        atomicAdd(&hist[q.x & (SBROWS - 1)], 1);
        atomicAdd(&hist[q.z & (SBROWS - 1)], 1);
    }
    if (tid == 0 && (total & 1)) atomicAdd(&hist[src[total - 1].x & (SBROWS - 1)], 1);
    __syncthreads();

    if (tid < 64) {
        int carry = 0;
        #pragma unroll
        for (int g = 0; g < SBROWS / 64; ++g) {
            int idx = g * 64 + tid;
            int h = hist[idx];
            int v = h;
            #pragma unroll
            for (int off = 1; off < 64; off <<= 1) {
                int t = __shfl_up(v, off, 64);
                if (tid >= off) v += t;
            }
            pref[idx] = carry + v - h;
            carry += __shfl(v, 63, 64);
        }
    }
    __syncthreads();

    uint2* dwin = dst + (size_t)s * SCAP;
    for (int i = tid; i < n2; i += 512) {
        uint4 q = src4[i];
        {
            int r = (int)(q.x & (SBROWS - 1));
            int p = pref[r] + atomicAdd(&fill[r], 1);
            uint2 o; o.x = q.x >> SBSHIFT; o.y = q.y;   // {col, valbits}
            dwin[p] = o;
        }
        {
            int r = (int)(q.z & (SBROWS - 1));
            int p = pref[r] + atomicAdd(&fill[r], 1);
            uint2 o; o.x = q.z >> SBSHIFT; o.y = q.w;
            dwin[p] = o;
        }
    }
    if (tid == 0 && (total & 1)) {
        uint2 pk = src[total - 1];
        int r = (int)(pk.x & (SBROWS - 1));
        int p = pref[r] + atomicAdd(&fill[r], 1);
        uint2 o; o.x = pk.x >> SBSHIFT; o.y = pk.y;
        dwin[p] = o;
    }
    if (tid < SBROWS) {
        int row = s * SBROWS + tid;
        if (row < NN) { row_start[row] = s * SCAP + pref[tid]; row_cnt[row] = hist[tid]; }
    }
}

// ---------- fused CSR SpMM: 8 edges/wave-instr (8 lanes x 8 bf16 per edge-row) ----------
__global__ __launch_bounds__(256) void spmm_csr_fused(const int* __restrict__ row_start,
                                                      const int* __restrict__ row_cnt,
                                                      const uint2* __restrict__ csr,
                                                      const unsigned short* __restrict__ x,
                                                      const float* __restrict__ noise_k,
                                                      unsigned short* __restrict__ ego_out,
                                                      float* __restrict__ acc,
                                                      int mode) {
    int row  = (blockIdx.x * 256 + threadIdx.x) >> 6;
    int lane = threadIdx.x & 63;
    if (row >= NN) return;
    const int slot = lane >> 3;                  // 0..7: which edge in the group of 8
    const int m    = lane & 7;                   // dims 8m..8m+7
    const unsigned moff = (unsigned)m << 3;      // element offset within the x row

    int s   = row_start[row];
    int end = s + row_cnt[row];

    float a0 = 0.f, a1 = 0.f, a2 = 0.f, a3 = 0.f;
    float a4 = 0.f, a5 = 0.f, a6 = 0.f, a7 = 0.f;
    float b0 = 0.f, b1 = 0.f, b2 = 0.f, b3 = 0.f;
    float b4 = 0.f, b5 = 0.f, b6 = 0.f, b7 = 0.f;
    int e = s;
    for (; e + 16 <= end; e += 16) {
        uint2 pA = csr[e + slot];
        uint2 pB = csr[e + 8 + slot];
        uint4 gA = *(const uint4*)(x + (((unsigned)pA.x) << 6) + moff);
        uint4 gB = *(const uint4*)(x + (((unsigned)pB.x) << 6) + moff);
        float vA = __uint_as_float(pA.y);
        float vB = __uint_as_float(pB.y);
        a0 += vA * bf16_lo(gA.x); a1 += vA * bf16_hi(gA.x);
        a2 += vA * bf16_lo(gA.y); a3 += vA * bf16_hi(gA.y);
        a4 += vA * bf16_lo(gA.z); a5 += vA * bf16_hi(gA.z);
        a6 += vA * bf16_lo(gA.w); a7 += vA * bf16_hi(gA.w);
        b0 += vB * bf16_lo(gB.x); b1 += vB * bf16_hi(gB.x);
        b2 += vB * bf16_lo(gB.y); b3 += vB * bf16_hi(gB.y);
        b4 += vB * bf16_lo(gB.z); b5 += vB * bf16_hi(gB.z);
        b6 += vB * bf16_lo(gB.w); b7 += vB * bf16_hi(gB.w);
    }
    for (; e < end; e += 8) {                    // masked tail groups of 8
        int idx = e + slot;
        uint2 p = make_uint2(0u, 0u);
        if (idx < end) p = csr[idx];
        uint4 g = *(const uint4*)(x + (((unsigned)p.x) << 6) + moff);
        float v = __uint_as_float(p.y);          // 0 for masked lanes
        a0 += v * bf16_lo(g.x); a1 += v * bf16_hi(g.x);
        a2 += v * bf16_lo(g.y); a3 += v * bf16_hi(g.y);
        a4 += v * bf16_lo(g.z); a5 += v * bf16_hi(g.z);
        a6 += v * bf16_lo(g.w); a7 += v * bf16_hi(g.w);
    }
    a0 += b0; a1 += b1; a2 += b2; a3 += b3;
    a4 += b4; a5 += b5; a6 += b6; a7 += b7;

    // combine the 8 slots: dims 8m..8m+7 summed across slot groups
    #pragma unroll
    for (int off = 8; off < 64; off <<= 1) {
        a0 += __shfl_xor(a0, off, 64);
        a1 += __shfl_xor(a1, off, 64);
        a2 += __shfl_xor(a2, off, 64);
        a3 += __shfl_xor(a3, off, 64);
        a4 += __shfl_xor(a4, off, 64);
        a5 += __shfl_xor(a5, off, 64);
        a6 += __shfl_xor(a6, off, 64);
        a7 += __shfl_xor(a7, off, 64);
    }

    if (slot == 0) {                             // 8 lanes handle the full row, 8 dims each
        size_t base4 = (size_t)row * 16 + ((unsigned)m << 1);   // float4 index
        float4 n0 = ((const float4*)noise_k)[base4];
        float4 n1 = ((const float4*)noise_k)[base4 + 1];
        float ss = n0.x * n0.x + n0.y * n0.y + n0.z * n0.z + n0.w * n0.w
                 + n1.x * n1.x + n1.y * n1.y + n1.z * n1.z + n1.w * n1.w;
        #pragma unroll
        for (int off = 1; off < 8; off <<= 1) ss += __shfl_xor(ss, off, 64);
        float inv = EPS_C / fmaxf(sqrtf(ss), 1e-12f);

        float e0 = fmaf(((a0 > 0.f) ? 1.f : ((a0 < 0.f) ? -1.f : 0.f)) * n0.x, inv, a0);
        float e1 = fmaf(((a1 > 0.f) ? 1.f : ((a1 < 0.f) ? -1.f : 0.f)) * n0.y, inv, a1);
        float e2 = fmaf(((a2 > 0.f) ? 1.f : ((a2 < 0.f) ? -1.f : 0.f)) * n0.z, inv, a2);
        float e3 = fmaf(((a3 > 0.f) ? 1.f : ((a3 < 0.f) ? -1.f : 0.f)) * n0.w, inv, a3);
        float e4 = fmaf(((a4 > 0.f) ? 1.f : ((a4 < 0.f) ? -1.f : 0.f)) * n1.x, inv, a4);
        float e5 = fmaf(((a5 > 0.f) ? 1.f : ((a5 < 0.f) ? -1.f : 0.f)) * n1.y, inv, a5);
        float e6 = fmaf(((a6 > 0.f) ? 1.f : ((a6 < 0.f) ? -1.f : 0.f)) * n1.z, inv, a6);
        float e7 = fmaf(((a7 > 0.f) ? 1.f : ((a7 < 0.f) ? -1.f : 0.f)) * n1.w, inv, a7);

        uint4 o;
        o.x = pack_bf16(e0, e1); o.y = pack_bf16(e2, e3);
        o.z = pack_bf16(e4, e5); o.w = pack_bf16(e6, e7);
        ((uint4*)ego_out)[(size_t)row * 8 + m] = o;

        float4* accp = (float4*)acc + base4;
        if (mode == 0) {
            accp[0] = make_float4(e0, e1, e2, e3);
            accp[1] = make_float4(e4, e5, e6, e7);
        } else if (mode == 1) {
            float4 c0 = accp[0], c1 = accp[1];
            c0.x += e0; c0.y += e1; c0.z += e2; c0.w += e3;
            c1.x += e4; c1.y += e5; c1.z += e6; c1.w += e7;
            accp[0] = c0; accp[1] = c1;
        } else {
            float4 c0 = accp[0], c1 = accp[1];
            c0.x = (c0.x + e0) * (1.0f / 3.0f); c0.y = (c0.y + e1) * (1.0f / 3.0f);
            c0.z = (c0.z + e2) * (1.0f / 3.0f); c0.w = (c0.w + e3) * (1.0f / 3.0f);
            c1.x = (c1.x + e4) * (1.0f / 3.0f); c1.y = (c1.y + e5) * (1.0f / 3.0f);
            c1.z = (c1.z + e6) * (1.0f / 3.0f); c1.w = (c1.w + e7) * (1.0f / 3.0f);
            accp[0] = c0; accp[1] = c1;
        }
    }
}

// ================= OLD PATH (verbatim fallback) =================
__global__ __launch_bounds__(256) void bucket_scatter_fixed(const int* __restrict__ rows,
                                                            const int* __restrict__ cols,
                                                            const float* __restrict__ vals,
                                                            int* __restrict__ bfill,
                                                            uint2* __restrict__ bbuf) {
    int e = blockIdx.x * 256 + threadIdx.x;
    if (e >= N_EDGES) return;
    int sub = blockIdx.x & (NSUB - 1);
    int r = rows[e];
    int b = r >> BSHIFT;
    int pos = atomicAdd(&bfill[b * NSUB + sub], 1);
    if (pos < CAPS) {
        uint2 pk;
        pk.x = (unsigned)(r & (BROWS - 1)) | ((unsigned)cols[e] << BSHIFT);
        pk.y = __float_as_uint(vals[e]);
        bbuf[(size_t)b * WIN + sub * CAPS + pos] = pk;
    }
}

__global__ __launch_bounds__(256) void bucket_sort_fixed(const int* __restrict__ bfill,
                                                         uint2* __restrict__ bbuf,
                                                         int* __restrict__ row_start,
                                                         int* __restrict__ row_cnt) {
    __shared__ uint2 buf[CAP];
    __shared__ int scnt[NSUB], soff[NSUB];
    __shared__ int h[BROWS], pref[BROWS], fill[BROWS];
    int b = blockIdx.x;
    int tid = threadIdx.x;
    if (tid < NSUB) {
        int c = bfill[b * NSUB + tid];
        scnt[tid] = (c < CAPS) ? c : CAPS;
    }
    if (tid < BROWS) { h[tid] = 0; fill[tid] = 0; }
    __syncthreads();
    if (tid == 0) {
        int run = 0;
        #pragma unroll
        for (int s = 0; s < NSUB; ++s) { soff[s] = run; run += scnt[s]; }
    }
    __syncthreads();
    int total = soff[NSUB - 1] + scnt[NSUB - 1];
    if (total > CAP) total = CAP;
    for (int s = 0; s < NSUB; ++s) {
        int c = scnt[s], off = soff[s];
        const uint2* src = bbuf + (size_t)b * WIN + s * CAPS;
        for (int i = tid; i < c; i += 256)
            if (off + i < CAP) buf[off + i] = src[i];
    }
    __syncthreads();
    for (int i = tid; i < total; i += 256) atomicAdd(&h[buf[i].x & (BROWS - 1)], 1);
    __syncthreads();
    if (tid == 0) {
        int run = 0;
        #pragma unroll
        for (int r = 0; r < BROWS; ++r) { pref[r] = run; run += h[r]; }
    }
    __syncthreads();
    uint2* dst = bbuf + (size_t)b * WIN;
    for (int i = tid; i < total; i += 256) {
        unsigned m = buf[i].x;
        int rl = (int)(m & (BROWS - 1));
        int pos = pref[rl] + atomicAdd(&fill[rl], 1);
        uint2 pk;
        pk.x = m >> BSHIFT;
        pk.y = buf[i].y;
        dst[pos] = pk;
    }
    if (tid < BROWS) {
        int row = b * BROWS + tid;
        if (row < NN) { row_start[row] = b * WIN + pref[tid]; row_cnt[row] = h[tid]; }
    }
}

// old-path spmm (wave-per-row, scalar bf16 gather) — kept for fallback branch
__global__ __launch_bounds__(256) void spmm_csr_old(const int* __restrict__ row_start,
                                                    const int* __restrict__ row_cnt,
                                                    const uint2* __restrict__ csr,
                                                    const unsigned short* __restrict__ x,
                                                    const float* __restrict__ noise_k,
                                                    unsigned short* __restrict__ ego_out,
                                                    float* __restrict__ acc,
                                                    int mode) {
    int row = (blockIdx.x * 256 + threadIdx.x) >> 6;
    int lane = threadIdx.x & 63;
    if (row >= NN) return;
    int s = row_start[row];
    int end = s + row_cnt[row];
    float a0 = 0.f, a1 = 0.f, a2 = 0.f, a3 = 0.f;
    int e = s;
    for (; e + 4 <= end; e += 4) {
        uint2 p0 = csr[e], p1 = csr[e + 1], p2 = csr[e + 2], p3 = csr[e + 3];
        a0 += __uint_as_float(p0.y) * bf16_to_f32(x[(size_t)p0.x * EMB + lane]);
        a1 += __uint_as_float(p1.y) * bf16_to_f32(x[(size_t)p1.x * EMB + lane]);
        a2 += __uint_as_float(p2.y) * bf16_to_f32(x[(size_t)p2.x * EMB + lane]);
        a3 += __uint_as_float(p3.y) * bf16_to_f32(x[(size_t)p3.x * EMB + lane]);
    }
    for (; e < end; ++e) {
        uint2 p = csr[e];
        a0 += __uint_as_float(p.y) * bf16_to_f32(x[(size_t)p.x * EMB + lane]);
    }
    float a = (a0 + a1) + (a2 + a3);
    size_t idx = (size_t)row * EMB + lane;
    float nv = noise_k[idx];
    float ss = nv * nv;
    #pragma unroll
    for (int off = 32; off >= 1; off >>= 1) ss += __shfl_xor(ss, off, 64);
    float nrm = fmaxf(sqrtf(ss), 1e-12f);
    float sgn = (a > 0.0f) ? 1.0f : ((a < 0.0f) ? -1.0f : 0.0f);
    float e1 = a + sgn * (nv / nrm) * EPS_C;
    ego_out[idx] = f32_to_bf16_rne(e1);
    if (mode == 0)      acc[idx] = e1;
    else if (mode == 1) acc[idx] += e1;
    else                acc[idx] = (acc[idx] + e1) * (1.0f / 3.0f);
}

// ---------- fallback: fp32 atomic path (needs 76.8 MB ws) ----------
__global__ __launch_bounds__(256) void concat_f32_kernel(const float* __restrict__ u,
                                                         const float* __restrict__ it,
                                                         float* __restrict__ out) {
    long i = (long)blockIdx.x * 256 + threadIdx.x;
    const long usz = (long)USER_NUM * EMB;
    const long tot = (long)NN * EMB;
    if (i >= tot) return;
    out[i] = (i < usz) ? u[i] : it[i - usz];
}

__global__ __launch_bounds__(256) void spmm_atomic_kernel(const int* __restrict__ rows,
                                                          const int* __restrict__ cols,
                                                          const float* __restrict__ vals,
                                                          const float* __restrict__ x,
                                                          float* __restrict__ y) {
    long t = (long)blockIdx.x * 256 + threadIdx.x;
    int e = (int)(t >> 6);
    int lane = (int)(t & 63);
    if (e >= N_EDGES) return;
    atomicAdd(&y[(long)rows[e] * EMB + lane], vals[e] * x[(long)cols[e] * EMB + lane]);
}

__global__ __launch_bounds__(256) void noise_acc_kernel(float* __restrict__ ego,
                                                        const float* __restrict__ noise_k,
                                                        float* __restrict__ acc,
                                                        int mode) {
    long t = (long)blockIdx.x * 256 + threadIdx.x;
    int node = (int)(t >> 6);
    int lane = (int)(t & 63);
    if (node >= NN) return;
    long idx = (long)node * EMB + lane;
    float nv = noise_k[idx];
    float s = nv * nv;
    #pragma unroll
    for (int off = 32; off >= 1; off >>= 1) s += __shfl_xor(s, off, 64);
    float nrm = fmaxf(sqrtf(s), 1e-12f);
    float e0 = ego[idx];
    float sgn = (e0 > 0.0f) ? 1.0f : ((e0 < 0.0f) ? -1.0f : 0.0f);
    float e1 = e0 + sgn * (nv / nrm) * EPS_C;
    ego[idx] = e1;
    if (mode == 0)      acc[idx] = e1;
    else if (mode == 1) acc[idx] += e1;
    else                acc[idx] = (acc[idx] + e1) * (1.0f / 3.0f);
}

extern "C" void kernel_launch(void* const* d_in, const int* in_sizes, int n_in,
                              void* d_out, int out_size, void* d_ws, size_t ws_size,
                              hipStream_t stream) {
    const float* user_emb   = (const float*)d_in[0];
    const float* item_emb   = (const float*)d_in[1];
    const float* user_proto = (const float*)d_in[2];
    const float* item_proto = (const float*)d_in[3];
    const int*   rows       = (const int*)d_in[4];
    const int*   cols       = (const int*)d_in[5];
    const float* vals       = (const float*)d_in[6];
    const float* noise      = (const float*)d_in[7];
    float* out = (float*)d_out;

    const size_t EGO_BF = ((size_t)NN * EMB * sizeof(unsigned short) + 255) & ~(size_t)255;
    const size_t NARR   = ((size_t)NN * sizeof(int) + 255) & ~(size_t)255;

    // ---- new path layout (~172 MB) ----
    const size_t SBUF_SZ  = (size_t)NSB * SCAP * sizeof(uint2);      // 66.0 MB
    const size_t DST_SZ   = (size_t)NSB * SCAP * sizeof(uint2);      // 66.0 MB (row-sorted)
    const size_t SFILL_SZ = ((size_t)NSB * SF_STRIDE * sizeof(int) + 255) & ~(size_t)255;
    const size_t required_new = 2 * EGO_BF + SBUF_SZ + DST_SZ + 2 * NARR + SFILL_SZ;

    // ---- old path layout (~131 MB) ----
    const size_t BBUF   = (size_t)NB * WIN * sizeof(uint2);
    const size_t FARR   = ((size_t)NB * NSUB * sizeof(int) + 255) & ~(size_t)255;
    const size_t required_old = 2 * EGO_BF + BBUF + 2 * NARR + FARR;

    float* acc = out;
    const int elemTotal  = NN * EMB;
    const int elemBlocks = (elemTotal + 255) / 256;
    const int vecBlocks  = (elemTotal / 4 + 255) / 256;
    const int edgeBlocks = (N_EDGES + 255) / 256;
    const int rowWaveBlocks = (NN + 3) / 4;

    if (ws_size >= required_new) {
        char* p = (char*)d_ws;
        unsigned short* egoA = (unsigned short*)p;  p += EGO_BF;
        unsigned short* egoB = (unsigned short*)p;  p += EGO_BF;
        uint2* sbuf          = (uint2*)p;           p += SBUF_SZ;
        uint2* dstbuf        = (uint2*)p;           p += DST_SZ;
        int* row_start       = (int*)p;             p += NARR;
        int* row_cnt         = (int*)p;             p += NARR;
        int* sfill           = (int*)p;             p += SFILL_SZ;

        concat_bf16_kernel<<<vecBlocks, 256, 0, stream>>>(user_emb, item_emb, egoA);
        hipMemsetAsync(sfill, 0, (size_t)NSB * SF_STRIDE * sizeof(int), stream);
        chunk_sort_scatter<<<NCH, 256, 0, stream>>>(rows, cols, vals, sfill, sbuf);
        bin_rowsort<<<NSB, 512, 0, stream>>>(sfill, sbuf, dstbuf, row_start, row_cnt);

        unsigned short* cur = egoA;
        unsigned short* nxt = egoB;
        for (int k = 0; k < 3; ++k) {
            int mode = (k == 0) ? 0 : ((k == 2) ? 2 : 1);
            spmm_csr_fused<<<rowWaveBlocks, 256, 0, stream>>>(
                row_start, row_cnt, dstbuf, cur,
                noise + (size_t)k * NN * EMB, nxt, acc, mode);
            unsigned short* t = cur; cur = nxt; nxt = t;
        }
    } else if (ws_size >= required_old) {
        char* p = (char*)d_ws;
        unsigned short* egoA = (unsigned short*)p;  p += EGO_BF;
        unsigned short* egoB = (unsigned short*)p;  p += EGO_BF;
        uint2* bbuf          = (uint2*)p;           p += BBUF;
        int* row_start       = (int*)p;             p += NARR;
        int* row_cnt         = (int*)p;             p += NARR;
        int* bfill           = (int*)p;             p += FARR;

        concat_bf16_kernel<<<vecBlocks, 256, 0, stream>>>(user_emb, item_emb, egoA);
        hipMemsetAsync(bfill, 0, (size_t)NB * NSUB * sizeof(int), stream);
        bucket_scatter_fixed<<<edgeBlocks, 256, 0, stream>>>(rows, cols, vals, bfill, bbuf);
        bucket_sort_fixed<<<NB, 256, 0, stream>>>(bfill, bbuf, row_start, row_cnt);

        unsigned short* cur = egoA;
        unsigned short* nxt = egoB;
        for (int k = 0; k < 3; ++k) {
            int mode = (k == 0) ? 0 : ((k == 2) ? 2 : 1);
            spmm_csr_old<<<rowWaveBlocks, 256, 0, stream>>>(
                row_start, row_cnt, bbuf, cur,
                noise + (size_t)k * NN * EMB, nxt, acc, mode);
            unsigned short* t = cur; cur = nxt; nxt = t;
        }
    } else {
        const size_t EGO_SZ = (size_t)NN * EMB * sizeof(float);
        float* fA = (float*)d_ws;
        float* fB = (float*)((char*)d_ws + EGO_SZ);
        concat_f32_kernel<<<elemBlocks, 256, 0, stream>>>(user_emb, item_emb, fA);
        float* cur = fA; float* nxt = fB;
        for (int k = 0; k < 3; ++k) {
            hipMemsetAsync(nxt, 0, EGO_SZ, stream);
            spmm_atomic_kernel<<<N_EDGES / 4, 256, 0, stream>>>(rows, cols, vals, cur, nxt);
            int mode = (k == 0) ? 0 : ((k == 2) ? 2 : 1);
            noise_acc_kernel<<<elemBlocks, 256, 0, stream>>>(
                nxt, noise + (size_t)k * NN * EMB, acc, mode);
            float* t = cur; cur = nxt; nxt = t;
        }
    }

    hipMemcpyAsync(out + (size_t)NN * EMB, user_proto,
                   (size_t)PROTO * EMB * sizeof(float), hipMemcpyDeviceToDevice, stream);
    hipMemcpyAsync(out + (size_t)NN * EMB + (size_t)PROTO * EMB, item_proto,
                   (size_t)PROTO * EMB * sizeof(float), hipMemcpyDeviceToDevice, stream);
}